// Round 4
// baseline (306.016 us; speedup 1.0000x reference)
//
#include <hip/hip_runtime.h>

// TokenMixer: out[n,b,c] = x_pos[n,b,c] * (1 - sigmoid(cos_sim(x_pre[n,b,:], x_pos[n,b,:])))
// N=4096, B=16, C=512 -> 65536 rows of 512 fp32.
//
// Round-4 changes vs round-3 (107 us, 3.76 TB/s eff):
//  1. Contiguous per-instruction coalescing: lane i owns float4 at i*16B within
//     each 1024-B half-row (was: 32-B lane chunks -> every vmem instr touched
//     32 half-used cache lines, 2x line-transaction rate on loads AND stores).
//  2. 2 rows per wave: 8 independent float4 loads in flight (~8KB/wave MLP)
//     before any dependent use; shuffle/epilogue amortized over 2x traffic.
// Reduction is order-agnostic so lane ownership remap is free.

constexpr int C_DIM = 512;
constexpr int ROWS  = 4096 * 16;   // 65536

__device__ __forceinline__ void partials(const float4& p, const float4& q,
                                         float& s_pre, float& s_pos, float& dot) {
    s_pre = fmaf(p.x, p.x, s_pre); s_pre = fmaf(p.y, p.y, s_pre);
    s_pre = fmaf(p.z, p.z, s_pre); s_pre = fmaf(p.w, p.w, s_pre);
    s_pos = fmaf(q.x, q.x, s_pos); s_pos = fmaf(q.y, q.y, s_pos);
    s_pos = fmaf(q.z, q.z, s_pos); s_pos = fmaf(q.w, q.w, s_pos);
    dot   = fmaf(p.x, q.x, dot);   dot   = fmaf(p.y, q.y, dot);
    dot   = fmaf(p.z, q.z, dot);   dot   = fmaf(p.w, q.w, dot);
}

__global__ __launch_bounds__(256) void tokenmixer_kernel(
    const float* __restrict__ pre,
    const float* __restrict__ pos,
    float* __restrict__ out)
{
    const int wave = (int)((blockIdx.x * 256u + threadIdx.x) >> 6);
    const int lane = (int)(threadIdx.x & 63u);

    // wave handles rows {2*wave, 2*wave+1}; lane owns float4 at lane*4 floats
    // inside each contiguous 1024-B (256-float) half-row segment.
    const size_t b = (size_t)wave * (2 * C_DIM) + (size_t)lane * 4;

    // row 0: segments [0,256) and [256,512); row 1: [512,768) and [768,1024)
    const float4 p0 = *reinterpret_cast<const float4*>(pre + b);
    const float4 p1 = *reinterpret_cast<const float4*>(pre + b + 256);
    const float4 p2 = *reinterpret_cast<const float4*>(pre + b + 512);
    const float4 p3 = *reinterpret_cast<const float4*>(pre + b + 768);
    const float4 q0 = *reinterpret_cast<const float4*>(pos + b);
    const float4 q1 = *reinterpret_cast<const float4*>(pos + b + 256);
    const float4 q2 = *reinterpret_cast<const float4*>(pos + b + 512);
    const float4 q3 = *reinterpret_cast<const float4*>(pos + b + 768);

    float sp0 = 0.f, sq0 = 0.f, d0 = 0.f;   // row 0
    float sp1 = 0.f, sq1 = 0.f, d1 = 0.f;   // row 1
    partials(p0, q0, sp0, sq0, d0);
    partials(p1, q1, sp0, sq0, d0);
    partials(p2, q2, sp1, sq1, d1);
    partials(p3, q3, sp1, sq1, d1);

    // 64-lane butterfly reduction, both rows interleaved (ILP=2 on DS chain)
#pragma unroll
    for (int m = 1; m < 64; m <<= 1) {
        sp0 += __shfl_xor(sp0, m, 64);
        sq0 += __shfl_xor(sq0, m, 64);
        d0  += __shfl_xor(d0,  m, 64);
        sp1 += __shfl_xor(sp1, m, 64);
        sq1 += __shfl_xor(sq1, m, 64);
        d1  += __shfl_xor(d1,  m, 64);
    }

    const float c0 = d0 / (fmaxf(sqrtf(sp0), 1e-12f) * fmaxf(sqrtf(sq0), 1e-12f));
    const float c1 = d1 / (fmaxf(sqrtf(sp1), 1e-12f) * fmaxf(sqrtf(sq1), 1e-12f));
    const float w0 = 1.0f / (1.0f + __expf(c0));   // 1 - sigmoid(c)
    const float w1 = 1.0f / (1.0f + __expf(c1));

    float4 o;
    o.x = q0.x * w0; o.y = q0.y * w0; o.z = q0.z * w0; o.w = q0.w * w0;
    *reinterpret_cast<float4*>(out + b) = o;
    o.x = q1.x * w0; o.y = q1.y * w0; o.z = q1.z * w0; o.w = q1.w * w0;
    *reinterpret_cast<float4*>(out + b + 256) = o;
    o.x = q2.x * w1; o.y = q2.y * w1; o.z = q2.z * w1; o.w = q2.w * w1;
    *reinterpret_cast<float4*>(out + b + 512) = o;
    o.x = q3.x * w1; o.y = q3.y * w1; o.z = q3.z * w1; o.w = q3.w * w1;
    *reinterpret_cast<float4*>(out + b + 768) = o;
}

extern "C" void kernel_launch(void* const* d_in, const int* in_sizes, int n_in,
                              void* d_out, int out_size, void* d_ws, size_t ws_size,
                              hipStream_t stream) {
    const float* pre = (const float*)d_in[0];
    const float* pos = (const float*)d_in[1];
    float* out = (float*)d_out;

    // 2 rows per wave, 4 waves per block -> 8 rows per block
    const int blocks = ROWS / 8;  // 8192
    tokenmixer_kernel<<<blocks, 256, 0, stream>>>(pre, pos, out);
}